// Round 1
// baseline (482.791 us; speedup 1.0000x reference)
//
#include <hip/hip_runtime.h>
#include <hip/hip_bf16.h>
#include <math.h>

#define BB 64
#define NN 1025
#define DD 768
#define HH 128
#define KK 256
#define TOK (BB*NN)          // 65600
#define OUT_XRED 0
#define OUT_IDX  (BB*(KK+1)*DD)            // 12,632,064
#define OUT_SC   (OUT_IDX + BB*(KK+1))     // + 16,448

// ---------------- K1: per-token mean / rstd in fp64 ----------------
__global__ __launch_bounds__(256) void k_stats(const float* __restrict__ x,
                                               double* __restrict__ mu,
                                               double* __restrict__ rstd)
{
    const int w    = threadIdx.x >> 6;
    const int lane = threadIdx.x & 63;
    const int tok  = blockIdx.x * 4 + w;          // 16400*4 = 65600 exact
    const float4* row = reinterpret_cast<const float4*>(x + (size_t)tok * DD);
    double s = 0.0, ss = 0.0;
    #pragma unroll
    for (int k = 0; k < 3; ++k) {
        float4 v = row[lane + 64*k];
        double a = v.x, b = v.y, c = v.z, d = v.w;
        s  += a + b + c + d;
        ss += a*a + b*b + c*c + d*d;
    }
    #pragma unroll
    for (int m = 32; m; m >>= 1) { s += __shfl_xor(s, m, 64); ss += __shfl_xor(ss, m, 64); }
    if (lane == 0) {
        double m_  = s / (double)DD;
        double var = ss / (double)DD - m_ * m_;
        mu[tok]   = m_;
        rstd[tok] = 1.0 / sqrt(var + 1e-5);
    }
}

// ---------------- K2: fused LN + (xn@W1+b1) -> gelu -> @W2+b2 -------
// block = 256 threads, 64 tokens x 128 cols, K chunks of 32 (fp64 acc)
#define TT 64
#define KC 32
__global__ __launch_bounds__(256) void k_mlp(const float* __restrict__ x,
    const float* __restrict__ lnw, const float* __restrict__ lnb,
    const float* __restrict__ w1,  const float* __restrict__ b1,
    const float* __restrict__ w2,  const float* __restrict__ b2,
    const double* __restrict__ mu, const double* __restrict__ rstd,
    double* __restrict__ sc, float* __restrict__ scores_out)
{
    __shared__ double xs[TT][36];      // 32 used; stride 36 keeps rows 16B-aligned
    __shared__ float  wls[KC][HH];
    __shared__ float  lnws[DD];
    __shared__ float  lnbs[DD];

    const int tid = threadIdx.x;
    const int jg  = tid & 31;          // col group: cols jg*4 .. jg*4+3
    const int ty  = tid >> 5;          // token group: tokens ty*8 .. ty*8+7
    const int tok0 = blockIdx.x * TT;

    for (int i = tid; i < DD; i += 256) { lnws[i] = lnw[i]; lnbs[i] = lnb[i]; }

    const int stok = tid >> 2;               // staging: token 0..63
    const int sd   = (tid & 3) * 8;          // staging: d offset 0/8/16/24
    const double smu = mu[tok0 + stok];
    const double srs = rstd[tok0 + stok];
    const float* srow = x + (size_t)(tok0 + stok) * DD;

    double acc[8][4];
    #pragma unroll
    for (int t = 0; t < 8; ++t)
        #pragma unroll
        for (int c = 0; c < 4; ++c) acc[t][c] = 0.0;

    for (int d0 = 0; d0 < DD; d0 += KC) {
        __syncthreads();
        // stage normalized x (fp64)
        {
            float4 a = *reinterpret_cast<const float4*>(srow + d0 + sd);
            float4 bq = *reinterpret_cast<const float4*>(srow + d0 + sd + 4);
            float xv[8] = {a.x,a.y,a.z,a.w,bq.x,bq.y,bq.z,bq.w};
            #pragma unroll
            for (int q = 0; q < 8; ++q) {
                int d = d0 + sd + q;
                xs[stok][sd+q] = ((double)xv[q] - smu) * srs * (double)lnws[d] + (double)lnbs[d];
            }
        }
        // stage w1 chunk (contiguous rows d0..d0+31)
        {
            const float4* wsrc = reinterpret_cast<const float4*>(w1 + (size_t)d0 * HH);
            float4* wdst = reinterpret_cast<float4*>(&wls[0][0]);
            #pragma unroll
            for (int q = 0; q < 4; ++q) wdst[tid + 256*q] = wsrc[tid + 256*q];
        }
        __syncthreads();
        // compute
        #pragma unroll
        for (int db = 0; db < KC; db += 4) {
            double wv[4][4];
            #pragma unroll
            for (int dd = 0; dd < 4; ++dd) {
                float4 w4 = *reinterpret_cast<const float4*>(&wls[db+dd][jg*4]);
                wv[dd][0] = w4.x; wv[dd][1] = w4.y; wv[dd][2] = w4.z; wv[dd][3] = w4.w;
            }
            #pragma unroll
            for (int t = 0; t < 8; ++t) {
                const double* xr = &xs[ty*8 + t][db];
                double x0 = xr[0], x1 = xr[1], x2 = xr[2], x3 = xr[3];
                #pragma unroll
                for (int c = 0; c < 4; ++c)
                    acc[t][c] += x0*wv[0][c] + x1*wv[1][c] + x2*wv[2][c] + x3*wv[3][c];
            }
        }
    }
    // epilogue: bias + exact gelu + dot with w2, half-wave reduce
    float4 b14 = *reinterpret_cast<const float4*>(b1 + jg*4);
    float4 w24 = *reinterpret_cast<const float4*>(w2 + jg*4);
    double b1d[4] = {b14.x, b14.y, b14.z, b14.w};
    double w2d[4] = {w24.x, w24.y, w24.z, w24.w};
    double b2d = (double)b2[0];
    #pragma unroll
    for (int t = 0; t < 8; ++t) {
        double p = 0.0;
        #pragma unroll
        for (int c = 0; c < 4; ++c) {
            double v = acc[t][c] + b1d[c];
            double g = 0.5 * v * (1.0 + erf(v * 0.70710678118654752440));
            p += g * w2d[c];
        }
        #pragma unroll
        for (int m = 16; m; m >>= 1) p += __shfl_xor(p, m, 32);
        if (jg == 0) {
            int tok = tok0 + ty*8 + t;
            double s = p + b2d;
            sc[tok] = s;
            int n = tok % NN;
            scores_out[tok] = (n == 0) ? 1.0e9f : (float)s;
        }
    }
}

// ---------------- K3: per-batch bitonic top-k (full 1024 sort) ------
__global__ __launch_bounds__(1024) void k_topk(const double* __restrict__ sc,
                                               float* __restrict__ idx_out)
{
    __shared__ double sk[1024];
    __shared__ int    si[1024];
    const int tid = threadIdx.x;
    const int b   = blockIdx.x;
    sk[tid] = sc[b*NN + 1 + tid];      // patch scores, token index tid+1
    si[tid] = tid + 1;
    __syncthreads();
    for (int k = 2; k <= 1024; k <<= 1) {
        for (int j = k >> 1; j > 0; j >>= 1) {
            int ixj = tid ^ j;
            if (ixj > tid) {
                double sa = sk[tid]; int ia = si[tid];
                double sb = sk[ixj]; int ib = si[ixj];
                // "before" order: larger score first; tie -> lower index first
                bool beforeB = (sb > sa) || (sb == sa && ib < ia);
                bool dirAsc  = ((tid & k) == 0);
                if (beforeB == dirAsc) {
                    sk[tid] = sb; si[tid] = ib;
                    sk[ixj] = sa; si[ixj] = ia;
                }
            }
            __syncthreads();
        }
    }
    if (tid == 0)  idx_out[b*(KK+1)] = 0.0f;
    if (tid < KK)  idx_out[b*(KK+1) + 1 + tid] = (float)si[tid];
}

// ---------------- K4: gather selected tokens ------------------------
__global__ __launch_bounds__(192) void k_gather(const float* __restrict__ x,
                                                const float* __restrict__ idx_out,
                                                float* __restrict__ xred)
{
    const int r = blockIdx.x;               // 0 .. 64*257-1
    const int b = r / (KK+1);
    const int idx = (int)(idx_out[r] + 0.5f);
    const float4* src = reinterpret_cast<const float4*>(x + ((size_t)b*NN + idx) * DD);
    float4* dst = reinterpret_cast<float4*>(xred + (size_t)r * DD);
    dst[threadIdx.x] = src[threadIdx.x];
}

extern "C" void kernel_launch(void* const* d_in, const int* in_sizes, int n_in,
                              void* d_out, int out_size, void* d_ws, size_t ws_size,
                              hipStream_t stream)
{
    const float* x   = (const float*)d_in[0];
    const float* lnw = (const float*)d_in[1];
    const float* lnb = (const float*)d_in[2];
    const float* w1  = (const float*)d_in[3];
    const float* b1  = (const float*)d_in[4];
    const float* w2  = (const float*)d_in[5];
    const float* b2  = (const float*)d_in[6];
    // d_in[7] = k (fixed at 256 for this problem shape)

    float* out   = (float*)d_out;
    float* xred  = out + OUT_XRED;
    float* idxf  = out + OUT_IDX;
    float* scout = out + OUT_SC;

    char* wsb = (char*)d_ws;
    double* mu   = (double*)(wsb);
    double* rstd = (double*)(wsb + (size_t)TOK*8);
    double* sc   = (double*)(wsb + (size_t)2*TOK*8);

    k_stats <<<TOK/4, 256, 0, stream>>>(x, mu, rstd);
    k_mlp   <<<TOK/TT, 256, 0, stream>>>(x, lnw, lnb, w1, b1, w2, b2, mu, rstd, sc, scout);
    k_topk  <<<BB, 1024, 0, stream>>>(sc, idxf);
    k_gather<<<BB*(KK+1), 192, 0, stream>>>(x, idxf, xred);
}

// Round 2
// 447.235 us; speedup vs baseline: 1.0795x; 1.0795x over previous
//
#include <hip/hip_runtime.h>
#include <hip/hip_bf16.h>
#include <math.h>

#define BB 64
#define NN 1025
#define DD 768
#define HH 128
#define KK 256
#define TOK (BB*NN)          // 65600
#define OUT_XRED 0
#define OUT_IDX  (BB*(KK+1)*DD)            // 12,632,064
#define OUT_SC   (OUT_IDX + BB*(KK+1))     // + 16,448

typedef double f64x4 __attribute__((ext_vector_type(4)));

// ---------------- K1: per-token mean / rstd in fp64 ----------------
__global__ __launch_bounds__(256) void k_stats(const float* __restrict__ x,
                                               double* __restrict__ mu,
                                               double* __restrict__ rstd)
{
    const int w    = threadIdx.x >> 6;
    const int lane = threadIdx.x & 63;
    const int tok  = blockIdx.x * 4 + w;          // 16400*4 = 65600 exact
    const float4* row = reinterpret_cast<const float4*>(x + (size_t)tok * DD);
    double s = 0.0, ss = 0.0;
    #pragma unroll
    for (int k = 0; k < 3; ++k) {
        float4 v = row[lane + 64*k];
        double a = v.x, b = v.y, c = v.z, d = v.w;
        s  += a + b + c + d;
        ss += a*a + b*b + c*c + d*d;
    }
    #pragma unroll
    for (int m = 32; m; m >>= 1) { s += __shfl_xor(s, m, 64); ss += __shfl_xor(ss, m, 64); }
    if (lane == 0) {
        double m_  = s / (double)DD;
        double var = ss / (double)DD - m_ * m_;
        mu[tok]   = m_;
        rstd[tok] = 1.0 / sqrt(var + 1e-5);
    }
}

// ---------------- K2: fused LN + GEMM (fp64 MFMA) + gelu + w2 -------
// 16-token tile per block, 4 waves; wave w owns cols [w*32, w*32+32).
// K chunks of 16 (4 MFMA k-steps), W1 chunk staged fp64 in LDS shared
// by all 4 waves; LN'd x staged fp64 as xs[k][tok].
#define TW 16
#define KC 16
__global__ __launch_bounds__(256) void k_mlp(const float* __restrict__ x,
    const float* __restrict__ lnw, const float* __restrict__ lnb,
    const float* __restrict__ w1,  const float* __restrict__ b1,
    const float* __restrict__ w2,  const float* __restrict__ b2,
    const double* __restrict__ mu, const double* __restrict__ rstd,
    double* __restrict__ sc, float* __restrict__ scores_out)
{
    __shared__ double wls[KC][HH];     // 16 KB: W1 chunk (fp64)
    __shared__ double xs[KC][TW];      // 2 KB: LN'd x, [k][tok]
    __shared__ double part[4][TW];     // 512 B: cross-wave partials

    const int tid  = threadIdx.x;
    const int wave = tid >> 6;
    const int lane = tid & 63;
    const int tok0 = blockIdx.x * TW;   // grid = 4100 exact
    const int colbase = wave * 32;

    // staging roles
    const int stok = tid >> 4;          // 0..15 token for x staging
    const int sk   = tid & 15;          // 0..15 k-offset for x staging
    const int wk   = tid >> 4;          // 0..15 W1 row
    const int wc   = (tid & 15) * 8;    // W1 col offset (8 floats)

    const double smu = mu[tok0 + stok];
    const double srs = rstd[tok0 + stok];
    const float* srow = x + (size_t)(tok0 + stok) * DD;

    f64x4 accA = {0.0, 0.0, 0.0, 0.0};
    f64x4 accB = {0.0, 0.0, 0.0, 0.0};

    for (int k0 = 0; k0 < DD; k0 += KC) {
        // issue global loads for this chunk BEFORE the barrier (regs only)
        float  xv = srow[k0 + sk];
        const float4* wp = reinterpret_cast<const float4*>(w1 + (size_t)(k0 + wk) * HH + wc);
        float4 wa = wp[0], wb = wp[1];
        float  lw = lnw[k0 + sk], lb = lnb[k0 + sk];

        __syncthreads();   // previous chunk's compute done

        xs[sk][stok] = ((double)xv - smu) * srs * (double)lw + (double)lb;
        wls[wk][wc+0] = (double)wa.x; wls[wk][wc+1] = (double)wa.y;
        wls[wk][wc+2] = (double)wa.z; wls[wk][wc+3] = (double)wa.w;
        wls[wk][wc+4] = (double)wb.x; wls[wk][wc+5] = (double)wb.y;
        wls[wk][wc+6] = (double)wb.z; wls[wk][wc+7] = (double)wb.w;

        __syncthreads();   // chunk staged

        #pragma unroll
        for (int kk = 0; kk < 4; ++kk) {
            const int krow = kk*4 + (lane >> 4);
            double a  = xs[krow][lane & 15];
            double bA = wls[krow][colbase + (lane & 15)];
            double bB = wls[krow][colbase + 16 + (lane & 15)];
            accA = __builtin_amdgcn_mfma_f64_16x16x4f64(a, bA, accA, 0, 0, 0);
            accB = __builtin_amdgcn_mfma_f64_16x16x4f64(a, bB, accB, 0, 0, 0);
        }
    }

    // epilogue: h = acc + b1; gelu exact; dot with w2; reduce
    // lane holds rows (lane>>4)*4 + r (r=0..3), cols colbase+{lane&15, 16+(lane&15)}
    const double b1A = (double)b1[colbase + (lane & 15)];
    const double b1B = (double)b1[colbase + 16 + (lane & 15)];
    const double w2A = (double)w2[colbase + (lane & 15)];
    const double w2B = (double)w2[colbase + 16 + (lane & 15)];
    const double is2 = 0.70710678118654752440;

    double psum[4];
    #pragma unroll
    for (int r = 0; r < 4; ++r) {
        double v0 = accA[r] + b1A;
        double v1 = accB[r] + b1B;
        double g0 = 0.5 * v0 * (1.0 + erf(v0 * is2));
        double g1 = 0.5 * v1 * (1.0 + erf(v1 * is2));
        double p = g0 * w2A + g1 * w2B;
        #pragma unroll
        for (int m = 8; m; m >>= 1) p += __shfl_xor(p, m, 64);
        psum[r] = p;
    }
    if ((lane & 15) == 0) {
        #pragma unroll
        for (int r = 0; r < 4; ++r) part[wave][(lane >> 4)*4 + r] = psum[r];
    }
    __syncthreads();
    if (tid < TW) {
        double s = part[0][tid] + part[1][tid] + part[2][tid] + part[3][tid] + (double)b2[0];
        int tok = tok0 + tid;
        sc[tok] = s;
        scores_out[tok] = ((tok % NN) == 0) ? 1.0e9f : (float)s;
    }
}

// ---------------- K3: per-batch bitonic top-k (full 1024 sort) ------
__global__ __launch_bounds__(1024) void k_topk(const double* __restrict__ sc,
                                               float* __restrict__ idx_out)
{
    __shared__ double sk_[1024];
    __shared__ int    si[1024];
    const int tid = threadIdx.x;
    const int b   = blockIdx.x;
    sk_[tid] = sc[b*NN + 1 + tid];      // patch scores, token index tid+1
    si[tid] = tid + 1;
    __syncthreads();
    for (int k = 2; k <= 1024; k <<= 1) {
        for (int j = k >> 1; j > 0; j >>= 1) {
            int ixj = tid ^ j;
            if (ixj > tid) {
                double sa = sk_[tid]; int ia = si[tid];
                double sb = sk_[ixj]; int ib = si[ixj];
                bool beforeB = (sb > sa) || (sb == sa && ib < ia);
                bool dirAsc  = ((tid & k) == 0);
                if (beforeB == dirAsc) {
                    sk_[tid] = sb; si[tid] = ib;
                    sk_[ixj] = sa; si[ixj] = ia;
                }
            }
            __syncthreads();
        }
    }
    if (tid == 0)  idx_out[b*(KK+1)] = 0.0f;
    if (tid < KK)  idx_out[b*(KK+1) + 1 + tid] = (float)si[tid];
}

// ---------------- K4: gather selected tokens ------------------------
__global__ __launch_bounds__(192) void k_gather(const float* __restrict__ x,
                                                const float* __restrict__ idx_out,
                                                float* __restrict__ xred)
{
    const int r = blockIdx.x;               // 0 .. 64*257-1
    const int b = r / (KK+1);
    const int idx = (int)(idx_out[r] + 0.5f);
    const float4* src = reinterpret_cast<const float4*>(x + ((size_t)b*NN + idx) * DD);
    float4* dst = reinterpret_cast<float4*>(xred + (size_t)r * DD);
    dst[threadIdx.x] = src[threadIdx.x];
}

extern "C" void kernel_launch(void* const* d_in, const int* in_sizes, int n_in,
                              void* d_out, int out_size, void* d_ws, size_t ws_size,
                              hipStream_t stream)
{
    const float* x   = (const float*)d_in[0];
    const float* lnw = (const float*)d_in[1];
    const float* lnb = (const float*)d_in[2];
    const float* w1  = (const float*)d_in[3];
    const float* b1  = (const float*)d_in[4];
    const float* w2  = (const float*)d_in[5];
    const float* b2  = (const float*)d_in[6];

    float* out   = (float*)d_out;
    float* xred  = out + OUT_XRED;
    float* idxf  = out + OUT_IDX;
    float* scout = out + OUT_SC;

    char* wsb = (char*)d_ws;
    double* mu   = (double*)(wsb);
    double* rstd = (double*)(wsb + (size_t)TOK*8);
    double* sc   = (double*)(wsb + (size_t)2*TOK*8);

    k_stats <<<TOK/4, 256, 0, stream>>>(x, mu, rstd);
    k_mlp   <<<TOK/TW, 256, 0, stream>>>(x, lnw, lnb, w1, b1, w2, b2, mu, rstd, sc, scout);
    k_topk  <<<BB, 1024, 0, stream>>>(sc, idxf);
    k_gather<<<BB*(KK+1), 192, 0, stream>>>(x, idxf, xred);
}

// Round 3
// 349.947 us; speedup vs baseline: 1.3796x; 1.2780x over previous
//
#include <hip/hip_runtime.h>
#include <hip/hip_bf16.h>
#include <math.h>

#define BB 64
#define NN 1025
#define DD 768
#define HH 128
#define KK 256
#define TOK (BB*NN)          // 65600
#define OUT_XRED 0
#define OUT_IDX  (BB*(KK+1)*DD)            // 12,632,064
#define OUT_SC   (OUT_IDX + BB*(KK+1))     // + 16,448

typedef double f64x4 __attribute__((ext_vector_type(4)));

// ---------------- K1: per-token mean / rstd in fp64 ----------------
__global__ __launch_bounds__(256) void k_stats(const float* __restrict__ x,
                                               double* __restrict__ mu,
                                               double* __restrict__ rstd)
{
    const int w    = threadIdx.x >> 6;
    const int lane = threadIdx.x & 63;
    const int tok  = blockIdx.x * 4 + w;          // 16400*4 = 65600 exact
    const float4* row = reinterpret_cast<const float4*>(x + (size_t)tok * DD);
    double s = 0.0, ss = 0.0;
    #pragma unroll
    for (int k = 0; k < 3; ++k) {
        float4 v = row[lane + 64*k];
        double a = v.x, b = v.y, c = v.z, d = v.w;
        s  += a + b + c + d;
        ss += a*a + b*b + c*c + d*d;
    }
    #pragma unroll
    for (int m = 32; m; m >>= 1) { s += __shfl_xor(s, m, 64); ss += __shfl_xor(ss, m, 64); }
    if (lane == 0) {
        double m_  = s / (double)DD;
        double var = ss / (double)DD - m_ * m_;
        mu[tok]   = m_;
        rstd[tok] = 1.0 / sqrt(var + 1e-5);
    }
}

// ---------------- K2: fused LN + GEMM (fp64 MFMA) + gelu + w2 -------
// 16-token tile per block, 4 waves; wave w owns cols [w*32, w*32+32).
// B-fragments (W1) loaded DIRECTLY global->reg (f32, L1/L2-hit) -> cvt f64.
// A (LN'd x) staged in LDS, XOR-swizzled xs[buf][k][t^k], double-buffered,
// one barrier per K-chunk of 16.
#define TW 16
#define KC 16
#define NCHUNK (DD/KC)
__global__ __launch_bounds__(256) void k_mlp(const float* __restrict__ x,
    const float* __restrict__ lnw, const float* __restrict__ lnb,
    const float* __restrict__ w1,  const float* __restrict__ b1,
    const float* __restrict__ w2,  const float* __restrict__ b2,
    const double* __restrict__ mu, const double* __restrict__ rstd,
    double* __restrict__ sc, float* __restrict__ scores_out)
{
    __shared__ double xs[2][KC][TW];   // 4 KB, swizzled col = t ^ k
    __shared__ double part[4][TW];

    const int tid  = threadIdx.x;
    const int wave = tid >> 6;
    const int lane = tid & 63;
    const int g    = lane >> 4;         // k-subrow 0..3
    const int t16  = lane & 15;         // token / col within fragment
    const int tok0 = blockIdx.x * TW;   // grid = 4100 exact
    const int colbase = wave * 32;

    // staging roles (x): thread stages x[tok0+stok][k0+sk]
    const int stok = tid >> 4;          // 0..15
    const int sk   = tid & 15;          // 0..15
    const double smu = mu[tok0 + stok];
    const double srs = rstd[tok0 + stok];
    const float* srow = x + (size_t)(tok0 + stok) * DD;

    // per-lane W1 base: row g (+4*kk + k0), col colbase + t16 (+16)
    const float* w1p = w1 + (size_t)g * HH + colbase + t16;

    f64x4 accA = {0.0, 0.0, 0.0, 0.0};
    f64x4 accB = {0.0, 0.0, 0.0, 0.0};

    // ---- prologue: stage chunk 0 ----
    float bf[8];
    #pragma unroll
    for (int kk = 0; kk < 4; ++kk) {
        bf[kk*2+0] = w1p[(kk*4)*HH];
        bf[kk*2+1] = w1p[(kk*4)*HH + 16];
    }
    {
        float xv = srow[sk];
        float lw = lnw[sk], lbv = lnb[sk];
        xs[0][sk][stok ^ sk] = ((double)xv - smu) * srs * (double)lw + (double)lbv;
    }
    __syncthreads();

    for (int c = 0; c < NCHUNK; ++c) {
        const int cur = c & 1;
        float bfn[8];
        if (c + 1 < NCHUNK) {
            const int k0n = (c + 1) * KC;
            #pragma unroll
            for (int kk = 0; kk < 4; ++kk) {
                bfn[kk*2+0] = w1p[(k0n + kk*4)*HH];
                bfn[kk*2+1] = w1p[(k0n + kk*4)*HH + 16];
            }
            float xv = srow[k0n + sk];
            float lw = lnw[k0n + sk], lbv = lnb[k0n + sk];
            xs[cur ^ 1][sk][stok ^ sk] = ((double)xv - smu) * srs * (double)lw + (double)lbv;
        }
        #pragma unroll
        for (int kk = 0; kk < 4; ++kk) {
            const int krow = kk*4 + g;
            double a  = xs[cur][krow][t16 ^ krow];
            accA = __builtin_amdgcn_mfma_f64_16x16x4f64(a, (double)bf[kk*2+0], accA, 0, 0, 0);
            accB = __builtin_amdgcn_mfma_f64_16x16x4f64(a, (double)bf[kk*2+1], accB, 0, 0, 0);
        }
        #pragma unroll
        for (int q = 0; q < 8; ++q) bf[q] = bfn[q];
        __syncthreads();
    }

    // epilogue: h = acc + b1; gelu exact; dot with w2; reduce
    // lane holds rows g*4 + r (r=0..3), cols colbase + {t16, 16+t16}
    const double b1A = (double)b1[colbase + t16];
    const double b1B = (double)b1[colbase + 16 + t16];
    const double w2A = (double)w2[colbase + t16];
    const double w2B = (double)w2[colbase + 16 + t16];
    const double is2 = 0.70710678118654752440;

    double psum[4];
    #pragma unroll
    for (int r = 0; r < 4; ++r) {
        double v0 = accA[r] + b1A;
        double v1 = accB[r] + b1B;
        double g0 = 0.5 * v0 * (1.0 + erf(v0 * is2));
        double g1 = 0.5 * v1 * (1.0 + erf(v1 * is2));
        double p = g0 * w2A + g1 * w2B;
        #pragma unroll
        for (int m = 8; m; m >>= 1) p += __shfl_xor(p, m, 64);
        psum[r] = p;
    }
    if (t16 == 0) {
        #pragma unroll
        for (int r = 0; r < 4; ++r) part[wave][g*4 + r] = psum[r];
    }
    __syncthreads();
    if (tid < TW) {
        double s = part[0][tid] + part[1][tid] + part[2][tid] + part[3][tid] + (double)b2[0];
        int tok = tok0 + tid;
        sc[tok] = s;
        scores_out[tok] = ((tok % NN) == 0) ? 1.0e9f : (float)s;
    }
}

// ---------------- K3: per-batch bitonic top-k (full 1024 sort) ------
__global__ __launch_bounds__(1024) void k_topk(const double* __restrict__ sc,
                                               float* __restrict__ idx_out)
{
    __shared__ double sk_[1024];
    __shared__ int    si[1024];
    const int tid = threadIdx.x;
    const int b   = blockIdx.x;
    sk_[tid] = sc[b*NN + 1 + tid];      // patch scores, token index tid+1
    si[tid] = tid + 1;
    __syncthreads();
    for (int k = 2; k <= 1024; k <<= 1) {
        for (int j = k >> 1; j > 0; j >>= 1) {
            int ixj = tid ^ j;
            if (ixj > tid) {
                double sa = sk_[tid]; int ia = si[tid];
                double sb = sk_[ixj]; int ib = si[ixj];
                bool beforeB = (sb > sa) || (sb == sa && ib < ia);
                bool dirAsc  = ((tid & k) == 0);
                if (beforeB == dirAsc) {
                    sk_[tid] = sb; si[tid] = ib;
                    sk_[ixj] = sa; si[ixj] = ia;
                }
            }
            __syncthreads();
        }
    }
    if (tid == 0)  idx_out[b*(KK+1)] = 0.0f;
    if (tid < KK)  idx_out[b*(KK+1) + 1 + tid] = (float)si[tid];
}

// ---------------- K4: gather selected tokens ------------------------
__global__ __launch_bounds__(192) void k_gather(const float* __restrict__ x,
                                                const float* __restrict__ idx_out,
                                                float* __restrict__ xred)
{
    const int r = blockIdx.x;               // 0 .. 64*257-1
    const int b = r / (KK+1);
    const int idx = (int)(idx_out[r] + 0.5f);
    const float4* src = reinterpret_cast<const float4*>(x + ((size_t)b*NN + idx) * DD);
    float4* dst = reinterpret_cast<float4*>(xred + (size_t)r * DD);
    dst[threadIdx.x] = src[threadIdx.x];
}

extern "C" void kernel_launch(void* const* d_in, const int* in_sizes, int n_in,
                              void* d_out, int out_size, void* d_ws, size_t ws_size,
                              hipStream_t stream)
{
    const float* x   = (const float*)d_in[0];
    const float* lnw = (const float*)d_in[1];
    const float* lnb = (const float*)d_in[2];
    const float* w1  = (const float*)d_in[3];
    const float* b1  = (const float*)d_in[4];
    const float* w2  = (const float*)d_in[5];
    const float* b2  = (const float*)d_in[6];

    float* out   = (float*)d_out;
    float* xred  = out + OUT_XRED;
    float* idxf  = out + OUT_IDX;
    float* scout = out + OUT_SC;

    char* wsb = (char*)d_ws;
    double* mu   = (double*)(wsb);
    double* rstd = (double*)(wsb + (size_t)TOK*8);
    double* sc   = (double*)(wsb + (size_t)2*TOK*8);

    k_stats <<<TOK/4, 256, 0, stream>>>(x, mu, rstd);
    k_mlp   <<<TOK/TW, 256, 0, stream>>>(x, lnw, lnb, w1, b1, w2, b2, mu, rstd, sc, scout);
    k_topk  <<<BB, 1024, 0, stream>>>(sc, idxf);
    k_gather<<<BB*(KK+1), 192, 0, stream>>>(x, idxf, xred);
}